// Round 4
// baseline (315.920 us; speedup 1.0000x reference)
//
#include <hip/hip_runtime.h>
#include <hip/hip_bf16.h>
#include <cstdint>
#include <math.h>

#define T 2048
#define NE 1024
#define NB 4

typedef __attribute__((ext_vector_type(8))) short short8;
typedef __attribute__((ext_vector_type(4))) short shortx4;
typedef __attribute__((ext_vector_type(4))) float floatx4;

__device__ __forceinline__ unsigned short f2bf(float f) {
    unsigned u = __float_as_uint(f);
    u += 0x7FFF + ((u >> 16) & 1);   // RNE
    return (unsigned short)(u >> 16);
}

__device__ __forceinline__ shortx4 cvt4(floatx4 f) {
    __hip_bfloat162 a = __float22bfloat162_rn(float2{f[0], f[1]});
    __hip_bfloat162 b = __float22bfloat162_rn(float2{f[2], f[3]});
    union { shortx4 s; unsigned u[2]; } r;
    r.u[0] = *(unsigned*)&a; r.u[1] = *(unsigned*)&b;
    return r.s;
}

__device__ __forceinline__ short8 cvt8(floatx4 f0, floatx4 f1) {
    __hip_bfloat162 a = __float22bfloat162_rn(float2{f0[0], f0[1]});
    __hip_bfloat162 b = __float22bfloat162_rn(float2{f0[2], f0[3]});
    __hip_bfloat162 c = __float22bfloat162_rn(float2{f1[0], f1[1]});
    __hip_bfloat162 d = __float22bfloat162_rn(float2{f1[2], f1[3]});
    union { short8 s; unsigned u[4]; } r;
    r.u[0] = *(unsigned*)&a; r.u[1] = *(unsigned*)&b;
    r.u[2] = *(unsigned*)&c; r.u[3] = *(unsigned*)&d;
    return r.s;
}

__device__ __forceinline__ void gl2lds(const void* g, void* l) {
    __builtin_amdgcn_global_load_lds(
        (const __attribute__((address_space(1))) void*)g,
        (__attribute__((address_space(3))) void*)l, 16, 0, 0);
}

// C[m,n] = scale * sum_k A[m,k]*B[n,k] (+ bias) — bf16 OR f32 in (AF32/BF32:
// reg-stage two float4, cvt to bf16, ds_write_b128 to the SAME lane-contiguous
// LDS dest gl2lds would use; source-chunk swizzle identical), f32/bf16 out.
// Tile (NWROW*64) x 128, BK=64, NWROW*128 threads (2*NWROW waves, 64x64/wave).
// LDS rows are 128B (8 chunks of 16B); logical chunk c of row r stored at
// physical chunk c^(r&7)  -> fragment ds_read_b128 spreads 16 lanes over all
// 32 banks (2-way, free) instead of 16-way on 4 banks.
// MODE: 0 plain | 1 xcd tm-band (ntnShift) | 2 tri 17/xcd | 3 PV pair {x,15-x}.
template<int NWROW, int BIAS_MODE, bool OUT_F32, bool CKLIM, bool DUAL, int MODE,
         bool AF32, bool BF32>
__global__ __launch_bounds__(NWROW * 128, 4) void gemm_bf16(
    const unsigned short* __restrict__ A0, const unsigned short* __restrict__ A1,
    const unsigned short* __restrict__ B0, const unsigned short* __restrict__ B1,
    const float* __restrict__ bias0, const float* __restrict__ bias1,
    void* __restrict__ C0, void* __restrict__ C1,
    int K, int lda, int ldb, int ldc,
    size_t sA, size_t sB, size_t sC, float scale, int ntnShift)
{
    constexpr int NTHR = NWROW * 128;
    constexpr int ABY = AF32 ? 4 : 2, BBY = BF32 ? 4 : 2;
    int tm, tn;
    const int bz = blockIdx.z;
    if (MODE == 2) {           // xcd-grouped lower-triangular decode
        const int i = blockIdx.x;
        int lin = (i & 7) * 17 + (i >> 3);
        tm = (int)((sqrtf(8.f * (float)lin + 1.f) - 1.f) * 0.5f);
        while ((tm + 1) * (tm + 2) / 2 <= lin) ++tm;
        while (tm * (tm + 1) / 2 > lin) --tm;
        tn = lin - tm * (tm + 1) / 2;
    } else if (MODE == 1) {    // xcd gets contiguous tm band x all tn
        const int bid = blockIdx.x;
        const int lin = (bid & 7) * (gridDim.x >> 3) + (bid >> 3);
        tm = lin >> ntnShift; tn = lin & ((1 << ntnShift) - 1);
    } else if (MODE == 3) {    // PV: xcd x -> tm {x, 15-x}, balanced
        const int xcd = blockIdx.x & 7, j = blockIdx.x >> 3;
        tm = (j & 1) ? xcd : (15 - xcd);
        tn = j >> 1;
    } else {
        tn = blockIdx.x; tm = blockIdx.y;
    }

    __shared__ __align__(16) char As[NWROW * 64 * 128];
    __shared__ __align__(16) char Bs[128 * 128];

    const int tid = threadIdx.x, lane = tid & 63, wave = tid >> 6;
    const int wm = wave % NWROW, wn = wave / NWROW;
    const int quad = lane >> 4, l15 = lane & 15;
    const int p = l15 & 7;                 // swizzle parity of fragment rows
    const int r8 = lane >> 3, c8 = lane & 7;

    const char* Ab = (const char*)((DUAL && bz) ? A1 : A0) + (size_t)bz * sA * ABY;
    const char* Bb = (const char*)((DUAL && bz) ? B1 : B0) + (size_t)bz * sB * BBY;
    const float* bias = (DUAL && bz) ? bias1 : bias0;

    int Keff = K;
    if (CKLIM) { int kl = (tm + 1) * 128; Keff = kl < K ? kl : K; }

    const size_t ldab = (size_t)lda * ABY, ldbb = (size_t)ldb * BBY;
    // staging: per call NTHR lanes cover NTHR/8 rows x 8 chunks; lane (r8,c8)
    // loads global chunk c8^r8 (swizzle). row&7 == r8 for every call/wave.
    const char* gA = Ab + (size_t)(tm * (NWROW * 64) + wave * 8 + r8) * ldab + (size_t)((c8 ^ r8) * (AF32 ? 32 : 16));
    const char* gB = Bb + (size_t)(tn * 128 + wave * 8 + r8) * ldbb + (size_t)((c8 ^ r8) * (BF32 ? 32 : 16));
    char* lA = As + wave * 1024;
    char* lB = Bs + wave * 1024;
    constexpr int BCALLS = 8 / NWROW;

    floatx4 acc[4][4] = {};

    for (int k0 = 0; k0 < Keff; k0 += 64) {
        const size_t kbA = (size_t)k0 * ABY;
        const size_t kbB = (size_t)k0 * BBY;
        if constexpr (AF32) {
            // 2-call batches: 16 temp VGPRs peak, cvt f32->bf16 inline
            #pragma unroll
            for (int c = 0; c < 4; c += 2) {
                const char* s0 = gA + (size_t)(c * NWROW * 16) * ldab + kbA;
                const char* s1 = gA + (size_t)((c + 1) * NWROW * 16) * ldab + kbA;
                floatx4 f0a = *(const floatx4*)(s0);
                floatx4 f0b = *(const floatx4*)(s0 + 16);
                floatx4 f1a = *(const floatx4*)(s1);
                floatx4 f1b = *(const floatx4*)(s1 + 16);
                *(short8*)(lA + c * NTHR * 16 + lane * 16)       = cvt8(f0a, f0b);
                *(short8*)(lA + (c + 1) * NTHR * 16 + lane * 16) = cvt8(f1a, f1b);
            }
        } else {
            #pragma unroll
            for (int c = 0; c < 4; ++c)
                gl2lds(gA + (size_t)(c * NWROW * 16) * ldab + kbA, lA + c * NTHR * 16);
        }
        if constexpr (BF32) {
            #pragma unroll
            for (int c = 0; c < BCALLS; c += 2) {
                const char* s0 = gB + (size_t)(c * NWROW * 16) * ldbb + kbB;
                const char* s1 = gB + (size_t)((c + 1) * NWROW * 16) * ldbb + kbB;
                floatx4 f0a = *(const floatx4*)(s0);
                floatx4 f0b = *(const floatx4*)(s0 + 16);
                floatx4 f1a = *(const floatx4*)(s1);
                floatx4 f1b = *(const floatx4*)(s1 + 16);
                *(short8*)(lB + c * NTHR * 16 + lane * 16)       = cvt8(f0a, f0b);
                *(short8*)(lB + (c + 1) * NTHR * 16 + lane * 16) = cvt8(f1a, f1b);
            }
        } else {
            #pragma unroll
            for (int c = 0; c < BCALLS; ++c)
                gl2lds(gB + (size_t)(c * NWROW * 16) * ldbb + kbB, lB + c * NTHR * 16);
        }
        __syncthreads();

        #pragma unroll
        for (int kk = 0; kk < 2; kk++) {
            short8 af[4], bfr[4];
            #pragma unroll
            for (int i = 0; i < 4; i++)
                af[i] = *(const short8*)(As + (wm * 64 + i * 16 + l15) * 128 + (((kk * 4 + quad) ^ p) << 4));
            #pragma unroll
            for (int j = 0; j < 4; j++)
                bfr[j] = *(const short8*)(Bs + (wn * 64 + j * 16 + l15) * 128 + (((kk * 4 + quad) ^ p) << 4));
            #pragma unroll
            for (int i = 0; i < 4; i++)
                #pragma unroll
                for (int j = 0; j < 4; j++)
                    acc[i][j] = __builtin_amdgcn_mfma_f32_16x16x32_bf16(af[i], bfr[j], acc[i][j], 0, 0, 0);
        }
        __syncthreads();
    }

    // Epilogue: C/D layout col = lane&15, row = quad*4 + reg  [verified]
    char* Cb = (char*)((DUAL && bz) ? C1 : C0) + (size_t)bz * sC * (OUT_F32 ? 4 : 2);
    #pragma unroll
    for (int i = 0; i < 4; i++) {
        #pragma unroll
        for (int j = 0; j < 4; j++) {
            const int n = tn * 128 + wn * 64 + j * 16 + l15;
            #pragma unroll
            for (int r = 0; r < 4; r++) {
                const int m = tm * (NWROW * 64) + wm * 64 + i * 16 + quad * 4 + r;
                float val = acc[i][j][r] * scale;
                if (BIAS_MODE == 1) val += bias[n];
                if (BIAS_MODE == 2) val += bias[m];
                if (OUT_F32) ((float*)Cb)[(size_t)m * ldc + n] = val;
                else         ((unsigned short*)Cb)[(size_t)m * ldc + n] = f2bf(val);
            }
        }
    }
}

// Weights-only f32->bf16 (6 MB out): wq,wk,wv. One float4 per thread.
__global__ __launch_bounds__(256) void cvt_w(
    const float* __restrict__ wq, const float* __restrict__ wk, const float* __restrict__ wv,
    unsigned short* __restrict__ wqb, unsigned short* __restrict__ wkb, unsigned short* __restrict__ wvb)
{
    const int W4 = NE * NE / 4;        // 2^18 float4 units
    int i = blockIdx.x * 256 + threadIdx.x;
    int sel = i >> 18, j = i & (W4 - 1);
    const float* s = sel == 0 ? wq : sel == 1 ? wk : wv;
    unsigned short* d = sel == 0 ? wqb : sel == 1 ? wkb : wvb;
    floatx4 f = ((const floatx4*)s)[j];
    ((shortx4*)d)[j] = cvt4(f);
}

// In-place causal softmax on bf16 S rows; touches only cols < ceil128(r+1).
__global__ __launch_bounds__(256) void softmax_causal(unsigned short* __restrict__ S)
{
    const int row = blockIdx.x;
    const int b = row >> 11, r = row & 2047;
    unsigned short* p = S + ((size_t)b * T + (size_t)r) * T;
    const int nv = r + 1;
    const int lim = ((r >> 7) + 1) * 128;
    const int tid = threadIdx.x, lane = tid & 63, wave = tid >> 6;
    const int c0 = tid * 8;
    const bool act = c0 < lim;

    short8 raw = {};
    if (act) raw = ((const short8*)p)[tid];
    float x[8];
    float mx = -3.0e38f;
    #pragma unroll
    for (int j = 0; j < 8; j++) {
        float vv = -3.0e38f;
        if (c0 + j < nv) vv = __uint_as_float((unsigned)(unsigned short)raw[j] << 16);
        x[j] = vv;
        mx = fmaxf(mx, vv);
    }
    #pragma unroll
    for (int off = 32; off > 0; off >>= 1)
        mx = fmaxf(mx, __shfl_xor(mx, off));
    __shared__ float smax[4], ssum[4];
    if (lane == 0) smax[wave] = mx;
    __syncthreads();
    mx = fmaxf(fmaxf(smax[0], smax[1]), fmaxf(smax[2], smax[3]));

    float s = 0.f;
    #pragma unroll
    for (int j = 0; j < 8; j++) {
        float e = 0.f;
        if (c0 + j < nv) e = __expf(x[j] - mx);
        x[j] = e;
        s += e;
    }
    #pragma unroll
    for (int off = 32; off > 0; off >>= 1)
        s += __shfl_xor(s, off);
    if (lane == 0) ssum[wave] = s;
    __syncthreads();
    const float inv = 1.f / (ssum[0] + ssum[1] + ssum[2] + ssum[3]);

    if (act) {
        short8 o;
        #pragma unroll
        for (int j = 0; j < 8; j++)
            o[j] = (short)f2bf(x[j] * inv);
        ((short8*)p)[tid] = o;
    }
}

extern "C" void kernel_launch(void* const* d_in, const int* in_sizes, int n_in,
                              void* d_out, int out_size, void* d_ws, size_t ws_size,
                              hipStream_t stream)
{
    const float* q    = (const float*)d_in[0];
    const float* k    = (const float*)d_in[1];
    const float* v    = (const float*)d_in[2];
    const float* wq_w = (const float*)d_in[3];
    const float* wq_b = (const float*)d_in[4];
    const float* wk_w = (const float*)d_in[5];
    const float* wk_b = (const float*)d_in[6];
    const float* wv_w = (const float*)d_in[7];
    const float* wv_b = (const float*)d_in[8];

    const size_t INEL = (size_t)NB * T * NE;

    unsigned short* qp = (unsigned short*)d_out;        // qp/kp scratch in d_out
    unsigned short* kp = qp + INEL;

    unsigned short* vpT = (unsigned short*)d_ws;        // 16MB
    unsigned short* S   = vpT + (size_t)NB * NE * T;    // 64MB; w* INSIDE S
    unsigned short* wqb = S;                            // read in steps 1-2,
    unsigned short* wkb = wqb + (size_t)NE * NE;        // S written in step 3
    unsigned short* wvb = wkb + (size_t)NE * NE;        // -> safe overlap

    dim3 blk(256);

    // 0) weights f32 -> bf16 (6 MB; q/k/v convert inline in GEMM staging)
    const int NCVT = 3 * (NE * NE / 4) / 256;
    cvt_w<<<dim3(NCVT), blk, 0, stream>>>(wq_w, wk_w, wv_w, wqb, wkb, wvb);

    // 1) qp/kp projections (DUAL, A = f32 q/k inline-cvt). 256x128 tile:
    //    M=8192/256=32, N=1024/128=8 -> 256 blk/z.
    gemm_bf16<4, 1, false, false, true, 1, true, false><<<dim3(256, 1, 2), dim3(512), 0, stream>>>(
        (const unsigned short*)q, (const unsigned short*)k, wqb, wkb, wq_b, wk_b,
        qp, kp, NE, NE, NE, NE, 0, 0, 0, 1.0f, 3);

    // 2) vpT[b] = Wv @ v_b^T + bv(row), B = f32 v inline-cvt. 256x128:
    //    M=1024/256=4, N=2048/128=16 -> 64 blk/z.
    gemm_bf16<4, 2, false, false, false, 1, false, true><<<dim3(64, 1, NB), dim3(512), 0, stream>>>(
        wvb, nullptr, (const unsigned short*)v, nullptr, wv_b, nullptr, vpT, nullptr,
        NE, NE, NE, T, 0, (size_t)T * NE, (size_t)NE * T, 1.0f, 4);

    // 3) S[b] = qp_b @ kp_b^T / 32 — 136 tri tiles (128x128), xcd-grouped
    gemm_bf16<2, 0, false, false, false, 2, false, false><<<dim3(136, 1, NB), blk, 0, stream>>>(
        qp, nullptr, kp, nullptr, nullptr, nullptr, S, nullptr,
        NE, NE, NE, T, (size_t)T * NE, (size_t)T * NE, (size_t)T * T, 0.03125f, 0);

    // 4) causal softmax
    softmax_causal<<<dim3(NB * T), blk, 0, stream>>>(S);

    // 5) O[b] = P_b @ vpT_b^T  (128x128, K=(tm+1)*128, xcd-balanced pairs)
    gemm_bf16<2, 0, true, true, false, 3, false, false><<<dim3(128, 1, NB), blk, 0, stream>>>(
        S, nullptr, vpT, nullptr, nullptr, nullptr, d_out, nullptr,
        T, T, T, NE, (size_t)T * T, (size_t)NE * T, (size_t)T * NE, 1.0f, 0);
}

// Round 5
// 294.698 us; speedup vs baseline: 1.0720x; 1.0720x over previous
//
#include <hip/hip_runtime.h>
#include <hip/hip_bf16.h>
#include <cstdint>
#include <math.h>

#define T 2048
#define NE 1024
#define NB 4

typedef __attribute__((ext_vector_type(8))) short short8;
typedef __attribute__((ext_vector_type(4))) short shortx4;
typedef __attribute__((ext_vector_type(4))) float floatx4;

__device__ __forceinline__ unsigned short f2bf(float f) {
    unsigned u = __float_as_uint(f);
    u += 0x7FFF + ((u >> 16) & 1);   // RNE
    return (unsigned short)(u >> 16);
}

__device__ __forceinline__ shortx4 cvt4(floatx4 f) {
    __hip_bfloat162 a = __float22bfloat162_rn(float2{f[0], f[1]});
    __hip_bfloat162 b = __float22bfloat162_rn(float2{f[2], f[3]});
    union { shortx4 s; unsigned u[2]; } r;
    r.u[0] = *(unsigned*)&a; r.u[1] = *(unsigned*)&b;
    return r.s;
}

__device__ __forceinline__ void gl2lds(const void* g, void* l) {
    __builtin_amdgcn_global_load_lds(
        (const __attribute__((address_space(1))) void*)g,
        (__attribute__((address_space(3))) void*)l, 16, 0, 0);
}

// C[m,n] = scale * sum_k A[m,k]*B[n,k] (+ bias) — bf16 in, f32/bf16 out.
// Tile (NWROW*64) x 128, BK=64, NWROW*128 threads (2*NWROW waves, 64x64/wave).
// LDS rows are 128B (8 chunks of 16B); logical chunk c of row r stored at
// physical chunk c^(r&7)  -> fragment ds_read_b128 spreads 16 lanes over all
// 32 banks (2-way, free) instead of 16-way on 4 banks. Staging implements the
// swizzle by permuting per-lane SOURCE addresses (LDS dest is lane-contiguous).
// MODE: 0 plain | 1 xcd tm-band (ntnShift) | 2 tri 17/xcd | 3 PV pair {x,15-x}.
// NWROW=2 (128x128) is the measured-best tile for this 2-barrier structure;
// r4 profiling showed 256-wide-M tiles are grid-limited to 2 blocks/CU.
template<int NWROW, int BIAS_MODE, bool OUT_F32, bool CKLIM, bool DUAL, int MODE>
__global__ __launch_bounds__(NWROW * 128, 4) void gemm_bf16(
    const unsigned short* __restrict__ A0, const unsigned short* __restrict__ A1,
    const unsigned short* __restrict__ B0, const unsigned short* __restrict__ B1,
    const float* __restrict__ bias0, const float* __restrict__ bias1,
    void* __restrict__ C0, void* __restrict__ C1,
    int K, int lda, int ldb, int ldc,
    size_t sA, size_t sB, size_t sC, float scale, int ntnShift)
{
    constexpr int NTHR = NWROW * 128;
    int tm, tn;
    const int bz = blockIdx.z;
    if (MODE == 2) {           // xcd-grouped lower-triangular decode
        const int i = blockIdx.x;
        int lin = (i & 7) * 17 + (i >> 3);
        tm = (int)((sqrtf(8.f * (float)lin + 1.f) - 1.f) * 0.5f);
        while ((tm + 1) * (tm + 2) / 2 <= lin) ++tm;
        while (tm * (tm + 1) / 2 > lin) --tm;
        tn = lin - tm * (tm + 1) / 2;
    } else if (MODE == 1) {    // xcd gets contiguous tm band x all tn
        const int bid = blockIdx.x;
        const int lin = (bid & 7) * (gridDim.x >> 3) + (bid >> 3);
        tm = lin >> ntnShift; tn = lin & ((1 << ntnShift) - 1);
    } else if (MODE == 3) {    // PV: xcd x -> tm {x, 15-x}, balanced
        const int xcd = blockIdx.x & 7, j = blockIdx.x >> 3;
        tm = (j & 1) ? xcd : (15 - xcd);
        tn = j >> 1;
    } else {
        tn = blockIdx.x; tm = blockIdx.y;
    }

    __shared__ __align__(16) char As[NWROW * 64 * 128];
    __shared__ __align__(16) char Bs[128 * 128];

    const int tid = threadIdx.x, lane = tid & 63, wave = tid >> 6;
    const int wm = wave % NWROW, wn = wave / NWROW;
    const int quad = lane >> 4, l15 = lane & 15;
    const int p = l15 & 7;                 // swizzle parity of fragment rows
    const int r8 = lane >> 3, c8 = lane & 7;

    const char* Ab = (const char*)((DUAL && bz) ? A1 : A0) + (size_t)bz * sA * 2;
    const char* Bb = (const char*)((DUAL && bz) ? B1 : B0) + (size_t)bz * sB * 2;
    const float* bias = (DUAL && bz) ? bias1 : bias0;

    int Keff = K;
    if (CKLIM) { int kl = (tm + 1) * 128; Keff = kl < K ? kl : K; }

    const size_t ldab = (size_t)lda * 2, ldbb = (size_t)ldb * 2;
    // staging: per call NTHR lanes cover NTHR/8 rows x 8 chunks; lane (r8,c8)
    // loads global chunk c8^r8 (swizzle). row&7 == r8 for every call/wave.
    const char* gA = Ab + (size_t)(tm * (NWROW * 64) + wave * 8 + r8) * ldab + (size_t)((c8 ^ r8) * 16);
    const char* gB = Bb + (size_t)(tn * 128 + wave * 8 + r8) * ldbb + (size_t)((c8 ^ r8) * 16);
    char* lA = As + wave * 1024;
    char* lB = Bs + wave * 1024;
    constexpr int BCALLS = 8 / NWROW;

    floatx4 acc[4][4] = {};

    for (int k0 = 0; k0 < Keff; k0 += 64) {
        const size_t kb = (size_t)k0 * 2;
        #pragma unroll
        for (int c = 0; c < 4; ++c)
            gl2lds(gA + (size_t)(c * NWROW * 16) * ldab + kb, lA + c * NTHR * 16);
        #pragma unroll
        for (int c = 0; c < BCALLS; ++c)
            gl2lds(gB + (size_t)(c * NWROW * 16) * ldbb + kb, lB + c * NTHR * 16);
        __syncthreads();

        #pragma unroll
        for (int kk = 0; kk < 2; kk++) {
            short8 af[4], bfr[4];
            #pragma unroll
            for (int i = 0; i < 4; i++)
                af[i] = *(const short8*)(As + (wm * 64 + i * 16 + l15) * 128 + (((kk * 4 + quad) ^ p) << 4));
            #pragma unroll
            for (int j = 0; j < 4; j++)
                bfr[j] = *(const short8*)(Bs + (wn * 64 + j * 16 + l15) * 128 + (((kk * 4 + quad) ^ p) << 4));
            #pragma unroll
            for (int i = 0; i < 4; i++)
                #pragma unroll
                for (int j = 0; j < 4; j++)
                    acc[i][j] = __builtin_amdgcn_mfma_f32_16x16x32_bf16(af[i], bfr[j], acc[i][j], 0, 0, 0);
        }
        __syncthreads();
    }

    // Epilogue: C/D layout col = lane&15, row = quad*4 + reg  [verified]
    char* Cb = (char*)((DUAL && bz) ? C1 : C0) + (size_t)bz * sC * (OUT_F32 ? 4 : 2);
    #pragma unroll
    for (int i = 0; i < 4; i++) {
        #pragma unroll
        for (int j = 0; j < 4; j++) {
            const int n = tn * 128 + wn * 64 + j * 16 + l15;
            #pragma unroll
            for (int r = 0; r < 4; r++) {
                const int m = tm * (NWROW * 64) + wm * 64 + i * 16 + quad * 4 + r;
                float val = acc[i][j][r] * scale;
                if (BIAS_MODE == 1) val += bias[n];
                if (BIAS_MODE == 2) val += bias[m];
                if (OUT_F32) ((float*)Cb)[(size_t)m * ldc + n] = val;
                else         ((unsigned short*)Cb)[(size_t)m * ldc + n] = f2bf(val);
            }
        }
    }
}

// Bulk f32->bf16: q,k,v then wq,wk,wv. One float4 per thread (r1 form — the
// best measured of 3 variants; ~43 µs, further tuning falsified twice).
__global__ __launch_bounds__(256) void cvt_all(
    const float* __restrict__ q, const float* __restrict__ k, const float* __restrict__ v,
    const float* __restrict__ wq, const float* __restrict__ wk, const float* __restrict__ wv,
    unsigned short* __restrict__ qb, unsigned short* __restrict__ kb, unsigned short* __restrict__ vb,
    unsigned short* __restrict__ wqb, unsigned short* __restrict__ wkb, unsigned short* __restrict__ wvb)
{
    const int IN4 = NB * T * NE / 4;   // 2^21
    const int W4  = NE * NE / 4;       // 2^18
    int i = blockIdx.x * 256 + threadIdx.x;
    const float* s; unsigned short* d; int j;
    if (i < 3 * IN4) {
        int sel = i >> 21; j = i & (IN4 - 1);
        s = sel == 0 ? q : sel == 1 ? k : v;
        d = sel == 0 ? qb : sel == 1 ? kb : vb;
    } else {
        int t2 = i - 3 * IN4; int sel = t2 >> 18; j = t2 & (W4 - 1);
        s = sel == 0 ? wq : sel == 1 ? wk : wv;
        d = sel == 0 ? wqb : sel == 1 ? wkb : wvb;
    }
    floatx4 f = ((const floatx4*)s)[j];
    ((shortx4*)d)[j] = cvt4(f);
}

// In-place causal softmax on bf16 S rows; touches only cols < ceil128(r+1).
__global__ __launch_bounds__(256) void softmax_causal(unsigned short* __restrict__ S)
{
    const int row = blockIdx.x;
    const int b = row >> 11, r = row & 2047;
    unsigned short* p = S + ((size_t)b * T + (size_t)r) * T;
    const int nv = r + 1;
    const int lim = ((r >> 7) + 1) * 128;
    const int tid = threadIdx.x, lane = tid & 63, wave = tid >> 6;
    const int c0 = tid * 8;
    const bool act = c0 < lim;

    short8 raw = {};
    if (act) raw = ((const short8*)p)[tid];
    float x[8];
    float mx = -3.0e38f;
    #pragma unroll
    for (int j = 0; j < 8; j++) {
        float vv = -3.0e38f;
        if (c0 + j < nv) vv = __uint_as_float((unsigned)(unsigned short)raw[j] << 16);
        x[j] = vv;
        mx = fmaxf(mx, vv);
    }
    #pragma unroll
    for (int off = 32; off > 0; off >>= 1)
        mx = fmaxf(mx, __shfl_xor(mx, off));
    __shared__ float smax[4], ssum[4];
    if (lane == 0) smax[wave] = mx;
    __syncthreads();
    mx = fmaxf(fmaxf(smax[0], smax[1]), fmaxf(smax[2], smax[3]));

    float s = 0.f;
    #pragma unroll
    for (int j = 0; j < 8; j++) {
        float e = 0.f;
        if (c0 + j < nv) e = __expf(x[j] - mx);
        x[j] = e;
        s += e;
    }
    #pragma unroll
    for (int off = 32; off > 0; off >>= 1)
        s += __shfl_xor(s, off);
    if (lane == 0) ssum[wave] = s;
    __syncthreads();
    const float inv = 1.f / (ssum[0] + ssum[1] + ssum[2] + ssum[3]);

    if (act) {
        short8 o;
        #pragma unroll
        for (int j = 0; j < 8; j++)
            o[j] = (short)f2bf(x[j] * inv);
        ((short8*)p)[tid] = o;
    }
}

extern "C" void kernel_launch(void* const* d_in, const int* in_sizes, int n_in,
                              void* d_out, int out_size, void* d_ws, size_t ws_size,
                              hipStream_t stream)
{
    const float* q    = (const float*)d_in[0];
    const float* k    = (const float*)d_in[1];
    const float* v    = (const float*)d_in[2];
    const float* wq_w = (const float*)d_in[3];
    const float* wq_b = (const float*)d_in[4];
    const float* wk_w = (const float*)d_in[5];
    const float* wk_b = (const float*)d_in[6];
    const float* wv_w = (const float*)d_in[7];
    const float* wv_b = (const float*)d_in[8];

    const size_t INEL = (size_t)NB * T * NE;

    unsigned short* qp = (unsigned short*)d_out;        // qp/kp scratch in d_out
    unsigned short* kp = qp + INEL;

    unsigned short* vpT = (unsigned short*)d_ws;        // 16MB
    unsigned short* S   = vpT + (size_t)NB * NE * T;    // 64MB; qb/kb/vb/w* inside
    unsigned short* qb  = S;
    unsigned short* kb  = qb + INEL;
    unsigned short* vb  = kb + INEL;
    unsigned short* wqb = vb + INEL;
    unsigned short* wkb = wqb + (size_t)NE * NE;
    unsigned short* wvb = wkb + (size_t)NE * NE;

    dim3 blk(256);

    // 0) all f32 -> bf16
    const int NCVT = (3 * (int)(INEL / 4) + 3 * NE * NE / 4 + 255) / 256;
    cvt_all<<<dim3(NCVT), blk, 0, stream>>>(q, k, v, wq_w, wk_w, wv_w, qb, kb, vb, wqb, wkb, wvb);

    // 1) qp/kp projections (DUAL). 128x128 tile: M=8192/128=64, N=1024/128=8
    //    -> 512 blk/z (4 blocks/CU vs 2 at the old 256x128 tile).
    gemm_bf16<2, 1, false, false, true, 1><<<dim3(512, 1, 2), blk, 0, stream>>>(
        qb, kb, wqb, wkb, wq_b, wk_b, qp, kp, NE, NE, NE, NE, 0, 0, 0, 1.0f, 3);

    // 2) vpT[b] = Wv @ v_b^T + bv(row). 128x128: M=1024/128=8, N=2048/128=16
    //    -> 128 blk/z.
    gemm_bf16<2, 2, false, false, false, 1><<<dim3(128, 1, NB), blk, 0, stream>>>(
        wvb, nullptr, vb, nullptr, wv_b, nullptr, vpT, nullptr,
        NE, NE, NE, T, 0, (size_t)T * NE, (size_t)NE * T, 1.0f, 4);

    // 3) S[b] = qp_b @ kp_b^T / 32 — 136 tri tiles (128x128), xcd-grouped
    gemm_bf16<2, 0, false, false, false, 2><<<dim3(136, 1, NB), blk, 0, stream>>>(
        qp, nullptr, kp, nullptr, nullptr, nullptr, S, nullptr,
        NE, NE, NE, T, (size_t)T * NE, (size_t)T * NE, (size_t)T * T, 0.03125f, 0);

    // 4) causal softmax
    softmax_causal<<<dim3(NB * T), blk, 0, stream>>>(S);

    // 5) O[b] = P_b @ vpT_b^T  (128x128, K=(tm+1)*128, xcd-balanced pairs)
    gemm_bf16<2, 0, true, true, false, 3><<<dim3(128, 1, NB), blk, 0, stream>>>(
        S, nullptr, vpT, nullptr, nullptr, nullptr, d_out, nullptr,
        T, T, T, NE, (size_t)T * T, (size_t)NE * T, (size_t)T * NE, 1.0f, 0);
}